// Round 1
// baseline (531.196 us; speedup 1.0000x reference)
//
#include <hip/hip_runtime.h>
#include <math.h>

// DigitCaps dynamic routing, fp32 baseline.
// Sizes fixed by the problem:
#define IN_CAPS 1152
#define OUT_CAPS 10
#define OUT_DIM 16
#define IN_DIM 8
#define BATCH 512
#define JD (OUT_CAPS * OUT_DIM)   // 160

// Blocking: each accum block handles G batches x ICHUNK input caps.
#define G 16
#define ICHUNK 32
#define NBCH (BATCH / G)          // 32
#define NICH (IN_CAPS / ICHUNK)   // 36
#define ATHREADS 512

// Workspace layout (floats):
//   S_part[NICH][BATCH][JD]  -- per-i-chunk partial s sums
//   V[BATCH][JD]             -- running sum of v_t (the routing "logit state")
// Total ~12.1 MB.

// mode: 0 = iter0 (c uniform 1/10, no logit pass), 1 = iters 1/2 (logits from V)
__global__ __launch_bounds__(ATHREADS) void accum_kernel(
    const float* __restrict__ X, const float* __restrict__ W,
    const float* __restrict__ V, float* __restrict__ S_part, int mode)
{
    // +1 pad: s_lds/V_lds row stride 161 floats -> bank = g mod 32, conflict-free
    __shared__ float V_lds[G][JD + 1];
    __shared__ float s_lds[G][JD + 1];

    const int tid = threadIdx.x;
    const int bid = blockIdx.x;
    const int bch = bid / NICH;
    const int ich = bid % NICH;

    // Stage V (only valid when mode!=0) and zero the s accumulator.
    for (int t = tid; t < G * JD; t += ATHREADS) {
        int g = t / JD, p = t % JD;
        V_lds[g][p] = (mode == 0) ? 0.f : V[(bch * G + g) * JD + p];
        s_lds[g][p] = 0.f;
    }
    __syncthreads();

    // lane layout: lane = i_sub*4 + gq  (4 g-duplicates share each W line)
    const int lane  = tid & 63;
    const int wave  = tid >> 6;
    const int gq    = lane & 3;
    const int isub  = (lane >> 2) & 15;
    const int gquad = wave & 3;          // waves 0..3 -> g quads (L1 reuse of W)
    const int ihalf = wave >> 2;         // waves 4..7 -> second 16 i's
    const int g = gquad * 4 + gq;        // 0..15
    const int b = bch * G + g;
    const int i = ich * ICHUNK + ihalf * 16 + isub;

    const float4* __restrict__ X4 = (const float4*)X;
    const float4* __restrict__ W4 = (const float4*)W;
    const int xoff  = (b * IN_CAPS + i) * 2;   // float4 units (8 f32 per (b,i))
    const int wbase = i * (JD * 2);            // float4 units (1280 f32 per i)

    const float4 xv0 = X4[xoff];
    const float4 xv1 = X4[xoff + 1];

    float c[OUT_CAPS];
    if (mode == 0) {
#pragma unroll
        for (int j = 0; j < OUT_CAPS; j++) c[j] = 0.1f;
    } else {
        // Pass A: logits L[j] = sum_d u_hat[j][d] * V[b][j][d]
        float L[OUT_CAPS];
#pragma unroll
        for (int j = 0; j < OUT_CAPS; j++) {
            float acc = 0.f;
#pragma unroll 4
            for (int d = 0; d < OUT_DIM; d++) {
                const float4 w0 = W4[wbase + (j * OUT_DIM + d) * 2];
                const float4 w1 = W4[wbase + (j * OUT_DIM + d) * 2 + 1];
                float u = w0.x * xv0.x + w0.y * xv0.y + w0.z * xv0.z + w0.w * xv0.w
                        + w1.x * xv1.x + w1.y * xv1.y + w1.z * xv1.z + w1.w * xv1.w;
                acc += u * V_lds[g][j * OUT_DIM + d];
            }
            L[j] = acc;
        }
        // softmax over the 10 out-capsules (thread-local)
        float m = L[0];
#pragma unroll
        for (int j = 1; j < OUT_CAPS; j++) m = fmaxf(m, L[j]);
        float Z = 0.f;
#pragma unroll
        for (int j = 0; j < OUT_CAPS; j++) { c[j] = __expf(L[j] - m); Z += c[j]; }
        const float rz = 1.f / Z;
#pragma unroll
        for (int j = 0; j < OUT_CAPS; j++) c[j] *= rz;
    }

    // Pass B: recompute u_hat, accumulate c*u_hat over this block's i's.
#pragma unroll
    for (int j = 0; j < OUT_CAPS; j++) {
        const float cj = c[j];
#pragma unroll 4
        for (int d = 0; d < OUT_DIM; d++) {
            const float4 w0 = W4[wbase + (j * OUT_DIM + d) * 2];
            const float4 w1 = W4[wbase + (j * OUT_DIM + d) * 2 + 1];
            float u = w0.x * xv0.x + w0.y * xv0.y + w0.z * xv0.z + w0.w * xv0.w
                    + w1.x * xv1.x + w1.y * xv1.y + w1.z * xv1.z + w1.w * xv1.w;
            float y = cj * u;
            // reduce over the 16 i_sub lanes (lane bits 2..5)
            y += __shfl_xor(y, 4);
            y += __shfl_xor(y, 8);
            y += __shfl_xor(y, 16);
            y += __shfl_xor(y, 32);
            if (isub == 0) atomicAdd(&s_lds[g][j * OUT_DIM + d], y);
        }
    }
    __syncthreads();

    // Write block-partial s to S_part[ich][b][jd]
    for (int t = tid; t < G * JD; t += ATHREADS) {
        int gg = t / JD, p = t % JD;
        S_part[((long)ich * BATCH + (bch * G + gg)) * JD + p] = s_lds[gg][p];
    }
}

// mode: 0 -> V = v (iter0), 1 -> V += v (iter1), 2 -> out = v (final)
__global__ __launch_bounds__(256) void squash_kernel(
    const float* __restrict__ S_part, float* __restrict__ V,
    float* __restrict__ out, int mode)
{
    const int t = blockIdx.x * 256 + threadIdx.x;  // 0 .. BATCH*JD-1
    float s = 0.f;
    for (int ic = 0; ic < NICH; ic++)
        s += S_part[(long)ic * BATCH * JD + t];
    // ||s||^2 over the 16 d's: threads of one (b,j) are lanes d = t&15
    float sq = s * s;
    sq += __shfl_xor(sq, 1);
    sq += __shfl_xor(sq, 2);
    sq += __shfl_xor(sq, 4);
    sq += __shfl_xor(sq, 8);
    const float v = s * sq / ((1.f + sq) * sqrtf(sq + 1e-8f));
    if (mode == 0)      V[t] = v;
    else if (mode == 1) V[t] += v;
    else                out[t] = v;
}

extern "C" void kernel_launch(void* const* d_in, const int* in_sizes, int n_in,
                              void* d_out, int out_size, void* d_ws, size_t ws_size,
                              hipStream_t stream)
{
    const float* X = (const float*)d_in[0];   // [512][1152][8]
    const float* W = (const float*)d_in[1];   // [1152][10][16][8]
    float* out = (float*)d_out;               // [512][10][16]

    float* S_part = (float*)d_ws;
    float* V      = S_part + (long)NICH * BATCH * JD;

    const dim3 ag(NBCH * NICH), ab(ATHREADS);
    const dim3 sg(BATCH * JD / 256), sb(256);

    // iter 0: c uniform
    accum_kernel<<<ag, ab, 0, stream>>>(X, W, V, S_part, 0);
    squash_kernel<<<sg, sb, 0, stream>>>(S_part, V, out, 0);   // V = v0
    // iter 1
    accum_kernel<<<ag, ab, 0, stream>>>(X, W, V, S_part, 1);
    squash_kernel<<<sg, sb, 0, stream>>>(S_part, V, out, 1);   // V += v1
    // iter 2 (final)
    accum_kernel<<<ag, ab, 0, stream>>>(X, W, V, S_part, 1);
    squash_kernel<<<sg, sb, 0, stream>>>(S_part, V, out, 2);   // out = v2
}